// Round 8
// baseline (49.604 us; speedup 1.0000x reference)
//
#include <hip/hip_runtime.h>

#define B 2
#define S 512
#define D 256
#define C2L 2.885390081777927f    // 2*log2(e)
#define LOG2E 1.4426950408889634f

// proj: Pt = (q @ W^T) * C2L.
//   EJ[b][e][i] = exp2(Pt)   (e-major: fused kernel j-streams, coalesced)
//   EN[b][i][e] = exp2(-Pt)  (row-major: fused kernel row factors, coalesced)
__global__ __launch_bounds__(256) void proj_kernel(const float* __restrict__ q,
                                                   const float* __restrict__ W,
                                                   float* __restrict__ EJ,
                                                   float* __restrict__ EN) {
    __shared__ float qlds[4 * D];
    const int t = threadIdx.x;
    const int b = blockIdx.x / (S / 4);
    const int i0 = (blockIdx.x % (S / 4)) * 4;
    const float* qbase = q + (size_t)(b * S + i0) * D;
    for (int idx = t; idx < 4 * D; idx += 256) qlds[idx] = qbase[idx];
    __syncthreads();
    const float* wr = W + (size_t)t * D;
    float a0 = 0.f, a1 = 0.f, a2 = 0.f, a3 = 0.f;
#pragma unroll 4
    for (int d = 0; d < D; ++d) {
        float w = wr[d];
        a0 = fmaf(qlds[d], w, a0);
        a1 = fmaf(qlds[D + d], w, a1);
        a2 = fmaf(qlds[2 * D + d], w, a2);
        a3 = fmaf(qlds[3 * D + d], w, a3);
    }
    a0 *= C2L; a1 *= C2L; a2 *= C2L; a3 *= C2L;
    float* ej = EJ + (size_t)(b * D + t) * S + i0;
    *(float4*)ej = make_float4(__builtin_amdgcn_exp2f(a0), __builtin_amdgcn_exp2f(a1),
                               __builtin_amdgcn_exp2f(a2), __builtin_amdgcn_exp2f(a3));
    EN[(size_t)(b * S + i0 + 0) * D + t] = __builtin_amdgcn_exp2f(-a0);
    EN[(size_t)(b * S + i0 + 1) * D + t] = __builtin_amdgcn_exp2f(-a1);
    EN[(size_t)(b * S + i0 + 2) * D + t] = __builtin_amdgcn_exp2f(-a2);
    EN[(size_t)(b * S + i0 + 3) * D + t] = __builtin_amdgcn_exp2f(-a3);
}

// Fused score + softmax + context. Block = 2 rows, 512 threads, thread t = column j.
// 512 blocks -> 2 blocks/CU, 4 waves/SIMD for latency hiding.
__global__ __launch_bounds__(512) void fused_kernel(const float* __restrict__ EJ,
                                                    const float* __restrict__ EN,
                                                    const float* __restrict__ vm,
                                                    const float* __restrict__ value,
                                                    float* __restrict__ att,
                                                    float* __restrict__ ctx) {
    __shared__ float en2[D][2];          // exp2(-Pt) for the 2 rows
    __shared__ float wl[D];              // -2*vm
    __shared__ float a2s[S][2];          // normalized attention (for ctx phase)
    __shared__ float part[2][8][64][4];  // ctx partials
    __shared__ float redm[2][8], reds[2][8];

    const int t = threadIdx.x;
    const int b = blockIdx.x >> 8;           // S/2 = 256 blocks per batch
    const int i0 = (blockIdx.x & 255) * 2;

    if (t < D) wl[t] = -2.f * vm[t];
    {
        const int e = t & 255, r = t >> 8;
        en2[e][r] = EN[((size_t)(b * S + i0 + r)) * D + e];
    }
    __syncthreads();

    // ---- score phase: s'[r] = sum_e (-2 vm_e) * sigma(2(Pj - Pr))  (shift cancels)
    float acc0 = 0.f, acc1 = 0.f;
    const float* ejp = EJ + (size_t)b * D * S + t;
#pragma unroll 8
    for (int e = 0; e < D; ++e) {
        float ev = ejp[(size_t)e * S];
        float w = wl[e];
        float2 f = *(const float2*)&en2[e][0];   // uniform address -> broadcast
        float y0 = fmaf(ev, f.x, 1.f);
        float y1 = fmaf(ev, f.y, 1.f);
        float r0 = __builtin_amdgcn_rcpf(y0);                            // trans pipe
        float r1 = __uint_as_float(0x7EF311C3u - __float_as_uint(y1));   // VALU pipe
        r1 = r1 * fmaf(-y1, r1, 2.f);
        r1 = r1 * fmaf(-y1, r1, 2.f);
        acc0 = fmaf(w, r0, acc0);
        acc1 = fmaf(w, r1, acc1);
    }

    // ---- softmax over j (one value per thread per row, 8 waves)
    const int lane = t & 63, wv = t >> 6;
    {
        float lm0 = acc0, lm1 = acc1;
#pragma unroll
        for (int off = 32; off; off >>= 1) {
            lm0 = fmaxf(lm0, __shfl_xor(lm0, off));
            lm1 = fmaxf(lm1, __shfl_xor(lm1, off));
        }
        if (lane == 0) { redm[0][wv] = lm0; redm[1][wv] = lm1; }
    }
    __syncthreads();
    float m0 = redm[0][0], m1 = redm[1][0];
#pragma unroll
    for (int w = 1; w < 8; ++w) {
        m0 = fmaxf(m0, redm[0][w]);
        m1 = fmaxf(m1, redm[1][w]);
    }
    float p0 = __builtin_amdgcn_exp2f((acc0 - m0) * LOG2E);
    float p1 = __builtin_amdgcn_exp2f((acc1 - m1) * LOG2E);
    {
        float ls0 = p0, ls1 = p1;
#pragma unroll
        for (int off = 32; off; off >>= 1) {
            ls0 += __shfl_xor(ls0, off);
            ls1 += __shfl_xor(ls1, off);
        }
        if (lane == 0) { reds[0][wv] = ls0; reds[1][wv] = ls1; }
    }
    __syncthreads();
    float s0 = 0.f, s1 = 0.f;
#pragma unroll
    for (int w = 0; w < 8; ++w) { s0 += reds[0][w]; s1 += reds[1][w]; }
    float a0 = p0 * __builtin_amdgcn_rcpf(s0);
    float a1 = p1 * __builtin_amdgcn_rcpf(s1);
    a2s[t][0] = a0;
    a2s[t][1] = a1;
    att[(size_t)(b * S + i0) * S + t] = a0;
    att[(size_t)(b * S + i0 + 1) * S + t] = a1;
    __syncthreads();

    // ---- context: thread -> (dq = t&63, js = t>>6); value read once per block
    {
        const int dq = t & 63, js = t >> 6;
        float4 c0 = {}, c1 = {};
        const float* vb = value + (size_t)b * S * D + (size_t)dq * 4;
#pragma unroll 4
        for (int jj = 0; jj < 64; ++jj) {
            int j = js * 64 + jj;
            float4 v = *(const float4*)(vb + (size_t)j * D);
            float w0 = a2s[j][0], w1 = a2s[j][1];
            c0.x = fmaf(w0, v.x, c0.x); c0.y = fmaf(w0, v.y, c0.y);
            c0.z = fmaf(w0, v.z, c0.z); c0.w = fmaf(w0, v.w, c0.w);
            c1.x = fmaf(w1, v.x, c1.x); c1.y = fmaf(w1, v.y, c1.y);
            c1.z = fmaf(w1, v.z, c1.z); c1.w = fmaf(w1, v.w, c1.w);
        }
        *(float4*)&part[0][js][dq][0] = c0;
        *(float4*)&part[1][js][dq][0] = c1;
    }
    __syncthreads();
    if (t < 128) {
        const int row = t >> 6, dq = t & 63;
        float4 sum = {};
#pragma unroll
        for (int js = 0; js < 8; ++js) {
            float4 pt = *(const float4*)&part[row][js][dq][0];
            sum.x += pt.x; sum.y += pt.y; sum.z += pt.z; sum.w += pt.w;
        }
        *(float4*)(ctx + (size_t)(b * S + i0 + row) * D + (size_t)dq * 4) = sum;
    }
}

extern "C" void kernel_launch(void* const* d_in, const int* in_sizes, int n_in,
                              void* d_out, int out_size, void* d_ws, size_t ws_size,
                              hipStream_t stream) {
    const float* q = (const float*)d_in[0];
    // d_in[1] = key (unused by the reference)
    const float* value = (const float*)d_in[2];
    const float* W = (const float*)d_in[3];
    const float* vm = (const float*)d_in[4];

    float* ctx = (float*)d_out;                    // [B,S,D]
    float* att = ctx + (size_t)B * S * D;          // [B,S,S]
    float* EJ = (float*)d_ws;                      // [B,D,S] exp2(Pt), 1 MB
    float* EN = EJ + (size_t)B * D * S;            // [B,S,D] exp2(-Pt), 1 MB

    proj_kernel<<<B * (S / 4), 256, 0, stream>>>(q, W, EJ, EN);
    fused_kernel<<<B * (S / 2), 512, 0, stream>>>(EJ, EN, vm, value, att, ctx);
}

// Round 9
// 44.570 us; speedup vs baseline: 1.1130x; 1.1130x over previous
//
#include <hip/hip_runtime.h>

#define B 2
#define S 512
#define D 256
#define C2L 2.885390081777927f    // 2*log2(e)
#define LOG2E 1.4426950408889634f

typedef float f32x2 __attribute__((ext_vector_type(2)));
typedef unsigned int u32x2 __attribute__((ext_vector_type(2)));

// proj: Pt = (q @ W^T) * C2L.
//   EJ4[b][e>>2][i][e&3] = exp2(Pt)  (float4-over-e: score loads dwordx4, coalesced)
//   EN[b][i][e] = exp2(-Pt)          (row-major: fused kernel row factors)
__global__ __launch_bounds__(256) void proj_kernel(const float* __restrict__ q,
                                                   const float* __restrict__ W,
                                                   float* __restrict__ EJ4,
                                                   float* __restrict__ EN) {
    __shared__ float qlds[4 * D];
    const int t = threadIdx.x;
    const int b = blockIdx.x / (S / 4);
    const int i0 = (blockIdx.x % (S / 4)) * 4;
    const float* qbase = q + (size_t)(b * S + i0) * D;
    for (int idx = t; idx < 4 * D; idx += 256) qlds[idx] = qbase[idx];
    __syncthreads();
    const float* wr = W + (size_t)t * D;
    float a0 = 0.f, a1 = 0.f, a2 = 0.f, a3 = 0.f;
#pragma unroll 4
    for (int d = 0; d < D; ++d) {
        float w = wr[d];
        a0 = fmaf(qlds[d], w, a0);
        a1 = fmaf(qlds[D + d], w, a1);
        a2 = fmaf(qlds[2 * D + d], w, a2);
        a3 = fmaf(qlds[3 * D + d], w, a3);
    }
    a0 *= C2L; a1 *= C2L; a2 *= C2L; a3 *= C2L;
    // EJ4 flat index: (((b*64 + (e>>2))*S + j)*4 + (e&3))
    float* ejb = EJ4 + (((size_t)(b * 64 + (t >> 2))) * S + i0) * 4 + (t & 3);
    ejb[0]  = __builtin_amdgcn_exp2f(a0);
    ejb[4]  = __builtin_amdgcn_exp2f(a1);
    ejb[8]  = __builtin_amdgcn_exp2f(a2);
    ejb[12] = __builtin_amdgcn_exp2f(a3);
    EN[(size_t)(b * S + i0 + 0) * D + t] = __builtin_amdgcn_exp2f(-a0);
    EN[(size_t)(b * S + i0 + 1) * D + t] = __builtin_amdgcn_exp2f(-a1);
    EN[(size_t)(b * S + i0 + 2) * D + t] = __builtin_amdgcn_exp2f(-a2);
    EN[(size_t)(b * S + i0 + 3) * D + t] = __builtin_amdgcn_exp2f(-a3);
}

// Fused score + softmax + context. Block = 4 rows, 512 threads, thread t = column j.
// Score sigmoids: rows (0,2) via HW rcp (trans pipe), rows (1,3) via packed
// Newton rcp (v_pk_* VALU) — pipes run concurrently.
__global__ __launch_bounds__(512) void fused_kernel(const float* __restrict__ EJ4,
                                                    const float* __restrict__ EN,
                                                    const float* __restrict__ vm,
                                                    const float* __restrict__ value,
                                                    float* __restrict__ att,
                                                    float* __restrict__ ctx) {
    __shared__ float en4[D][4];          // comps = rows (i0, i0+2, i0+1, i0+3)
    __shared__ float wl[D];              // -2*vm
    __shared__ float a4[S][4];           // normalized attention rows
    __shared__ float part[4][8][64][4];  // ctx partials
    __shared__ float redm[4][8], reds[4][8];

    const int t = threadIdx.x;
    const int b = blockIdx.x >> 7;           // S/4 = 128 blocks per batch
    const int i0 = (blockIdx.x & 127) * 4;

    if (t < D) wl[t] = -2.f * vm[t];
    {
        const int e = t & 255, rsel = t >> 8;      // rsel 0: rows i0,i0+2 -> comps 0,1
        float v0 = EN[((size_t)(b * S + i0 + rsel)) * D + e];        // i0 or i0+1
        float v2 = EN[((size_t)(b * S + i0 + rsel + 2)) * D + e];    // i0+2 or i0+3
        en4[e][rsel * 2 + 0] = v0;
        en4[e][rsel * 2 + 1] = v2;
    }
    __syncthreads();

    // ---- score: s'[r] = sum_e (-2 vm_e) * sigma(2(Pj - Pr))  (shift cancels)
    f32x2 acc02 = {0.f, 0.f}, acc13 = {0.f, 0.f};
    const float4* ejp = (const float4*)EJ4 + (size_t)b * 64 * S + t;
    const f32x2 one2 = {1.f, 1.f}, two2 = {2.f, 2.f};
    const u32x2 magic = {0x7EF311C3u, 0x7EF311C3u};
#pragma unroll 4
    for (int g = 0; g < 64; ++g) {
        float4 ev4 = ejp[(size_t)g * S];
#pragma unroll
        for (int c = 0; c < 4; ++c) {
            const float ev = (c == 0) ? ev4.x : (c == 1) ? ev4.y : (c == 2) ? ev4.z : ev4.w;
            const int e = g * 4 + c;
            float4 f = *(const float4*)&en4[e][0];   // uniform -> LDS broadcast
            const float w = wl[e];
            f32x2 ev2 = {ev, ev};
            f32x2 f02 = {f.x, f.y}, f13 = {f.z, f.w};
            f32x2 y02 = ev2 * f02 + one2;            // v_pk_fma_f32
            f32x2 y13 = ev2 * f13 + one2;
            f32x2 r02 = {__builtin_amdgcn_rcpf(y02.x),
                         __builtin_amdgcn_rcpf(y02.y)};          // trans pipe
            u32x2 ui = magic - __builtin_bit_cast(u32x2, y13);   // VALU pipe
            f32x2 rn = __builtin_bit_cast(f32x2, ui);
            rn = rn * (two2 - y13 * rn);
            rn = rn * (two2 - y13 * rn);
            f32x2 w2 = {w, w};
            acc02 += w2 * r02;
            acc13 += w2 * rn;
        }
    }
    float accR[4] = {acc02.x, acc13.x, acc02.y, acc13.y};   // rows i0..i0+3

    // ---- softmax over j (one value per thread per row, 8 waves)
    const int lane = t & 63, wv = t >> 6;
#pragma unroll
    for (int r = 0; r < 4; ++r) {
        float lm = accR[r];
#pragma unroll
        for (int off = 32; off; off >>= 1) lm = fmaxf(lm, __shfl_xor(lm, off));
        if (lane == 0) redm[r][wv] = lm;
    }
    __syncthreads();
    float p[4];
#pragma unroll
    for (int r = 0; r < 4; ++r) {
        float m = redm[r][0];
#pragma unroll
        for (int w = 1; w < 8; ++w) m = fmaxf(m, redm[r][w]);
        p[r] = __builtin_amdgcn_exp2f((accR[r] - m) * LOG2E);
        float ls = p[r];
#pragma unroll
        for (int off = 32; off; off >>= 1) ls += __shfl_xor(ls, off);
        if (lane == 0) reds[r][wv] = ls;
    }
    __syncthreads();
#pragma unroll
    for (int r = 0; r < 4; ++r) {
        float s = 0.f;
#pragma unroll
        for (int w = 0; w < 8; ++w) s += reds[r][w];
        float a = p[r] * __builtin_amdgcn_rcpf(s);
        a4[t][r] = a;
        att[(size_t)(b * S + i0 + r) * S + t] = a;
    }
    __syncthreads();

    // ---- context: thread -> (dq = t&63, js = t>>6); value read once per block
    {
        const int dq = t & 63, js = t >> 6;
        float4 acc0 = {}, acc1 = {}, acc2 = {}, acc3 = {};
        const float* vb = value + (size_t)b * S * D + (size_t)dq * 4;
#pragma unroll 4
        for (int jj = 0; jj < 64; ++jj) {
            int j = js * 64 + jj;
            float4 v = *(const float4*)(vb + (size_t)j * D);
            float w0 = a4[j][0], w1 = a4[j][1], w2 = a4[j][2], w3 = a4[j][3];
            acc0.x = fmaf(w0, v.x, acc0.x); acc0.y = fmaf(w0, v.y, acc0.y);
            acc0.z = fmaf(w0, v.z, acc0.z); acc0.w = fmaf(w0, v.w, acc0.w);
            acc1.x = fmaf(w1, v.x, acc1.x); acc1.y = fmaf(w1, v.y, acc1.y);
            acc1.z = fmaf(w1, v.z, acc1.z); acc1.w = fmaf(w1, v.w, acc1.w);
            acc2.x = fmaf(w2, v.x, acc2.x); acc2.y = fmaf(w2, v.y, acc2.y);
            acc2.z = fmaf(w2, v.z, acc2.z); acc2.w = fmaf(w2, v.w, acc2.w);
            acc3.x = fmaf(w3, v.x, acc3.x); acc3.y = fmaf(w3, v.y, acc3.y);
            acc3.z = fmaf(w3, v.z, acc3.z); acc3.w = fmaf(w3, v.w, acc3.w);
        }
        *(float4*)&part[0][js][dq][0] = acc0;
        *(float4*)&part[1][js][dq][0] = acc1;
        *(float4*)&part[2][js][dq][0] = acc2;
        *(float4*)&part[3][js][dq][0] = acc3;
    }
    __syncthreads();
    if (t < 256) {
        const int row = t >> 6, dq = t & 63;
        float4 sum = {};
#pragma unroll
        for (int js = 0; js < 8; ++js) {
            float4 pt = *(const float4*)&part[row][js][dq][0];
            sum.x += pt.x; sum.y += pt.y; sum.z += pt.z; sum.w += pt.w;
        }
        *(float4*)(ctx + (size_t)(b * S + i0 + row) * D + (size_t)dq * 4) = sum;
    }
}

extern "C" void kernel_launch(void* const* d_in, const int* in_sizes, int n_in,
                              void* d_out, int out_size, void* d_ws, size_t ws_size,
                              hipStream_t stream) {
    const float* q = (const float*)d_in[0];
    // d_in[1] = key (unused by the reference)
    const float* value = (const float*)d_in[2];
    const float* W = (const float*)d_in[3];
    const float* vm = (const float*)d_in[4];

    float* ctx = (float*)d_out;                    // [B,S,D]
    float* att = ctx + (size_t)B * S * D;          // [B,S,S]
    float* EJ4 = (float*)d_ws;                     // [B][64][S][4] exp2(Pt), 1 MB
    float* EN = EJ4 + (size_t)B * D * S;           // [B,S,D] exp2(-Pt), 1 MB

    proj_kernel<<<B * (S / 4), 256, 0, stream>>>(q, W, EJ4, EN);
    fused_kernel<<<B * (S / 4), 512, 0, stream>>>(EJ4, EN, vm, value, att, ctx);
}